// Round 7
// baseline (640.597 us; speedup 1.0000x reference)
//
#include <hip/hip_runtime.h>

#define NB 4      // batch
#define NC 32     // width (channels)
#define NH 256
#define NW 256
#define NM 16     // modes per dim
constexpr int NPIX = NH * NW;                 // 65536
constexpr int NP = NB * NC * NPIX;            // floats per per-o tensor
constexpr int ZG = NB * NC * NM * NM * 2;     // floats per g for zred/zmix

typedef short bf16x8 __attribute__((ext_vector_type(8)));
typedef float f32x4  __attribute__((ext_vector_type(4)));
typedef unsigned short u16;

#define MFMA16(a, b, c) __builtin_amdgcn_mfma_f32_16x16x32_bf16(a, b, c, 0, 0, 0)

__device__ __forceinline__ u16 f2bf(float f) {
    unsigned u = __float_as_uint(f);
    u += 0x7FFFu + ((u >> 16) & 1u);
    return (u16)(u >> 16);
}
__device__ __forceinline__ float bf2f(u16 h) {
    return __uint_as_float(((unsigned)h) << 16);
}

// fast erf (A&S 7.1.26, |err| <= 1.5e-7) based exact-GELU
__device__ __forceinline__ float gelu_fast(float v) {
    const float ax = fabsf(v) * 0.70710678118654752f;
    const float t = __builtin_amdgcn_rcpf(1.0f + 0.3275911f * ax);
    const float y = t * (0.254829592f + t * (-0.284496736f + t * (1.421413741f +
                    t * (-1.453152027f + t * 1.061405429f))));
    const float e = __expf(-ax * ax);
    float er = 1.0f - y * e;
    er = copysignf(er, v);
    return 0.5f * v * (1.0f + er);
}

// ---------------------------------------------------------------------------
// Table prep: cw (inv B-operand, [n=256][k=32]) and eb (fwd DFT matrix,
// [row=32][w=256], scaled 1/16; applied twice -> 1/256 ortho norm).
// ---------------------------------------------------------------------------
__global__ __launch_bounds__(256) void tab_prep(
    u16* __restrict__ cwhi, u16* __restrict__ cwlo,
    u16* __restrict__ ebhi, u16* __restrict__ eblo)
{
    const int id = blockIdx.x * 256 + threadIdx.x;   // 0..16383
    if (id < 8192) {
        const int nn = id >> 5, k = id & 31;
        const int m = ((k & 15) * nn) & 255;
        float s, c;
        sincospif((float)m * (2.0f / 256.0f), &s, &c);
        const float v = (k < 16) ? c : s;
        const u16 hi = f2bf(v);
        cwhi[id] = hi;
        cwlo[id] = f2bf(v - bf2f(hi));
    } else {
        const int id2 = id - 8192;
        const int row = id2 >> 8, w = id2 & 255;
        const int m = ((row & 15) * w) & 255;
        float s, c;
        sincospif((float)m * (2.0f / 256.0f), &s, &c);
        const float v = 0.0625f * ((row < 16) ? c : s);
        const u16 hi = f2bf(v);
        ebhi[id2] = hi;
        eblo[id2] = f2bf(v - bf2f(hi));
    }
}

// ---------------------------------------------------------------------------
// fwd stage 1 (LIFT path only now): Y[c][combo][h] from x rows.
// grid (c=32, b=4, hq=4), block 256.
// ---------------------------------------------------------------------------
__global__ __launch_bounds__(256) void fwd_s1_lift(
    const float* __restrict__ src,      // x[B,3,H,W]
    const float* __restrict__ lift_w,
    const float* __restrict__ lift_b,
    const u16* __restrict__ ebhi,
    const u16* __restrict__ eblo,
    u16* __restrict__ yhi,
    u16* __restrict__ ylo)
{
    __shared__ u16 TrHi[64][34], TrLo[64][34];   // [h-local][combo], pad 34

    const int tid = threadIdx.x;
    const int c  = blockIdx.x;
    const int gb = blockIdx.y;          // == b
    const int hq = blockIdx.z;
    const int b  = gb & 3;
    const int wv = tid >> 6, lane = tid & 63;
    const int mrow = lane & 15, q = lane >> 4;
    const int hbase = hq * 64 + wv * 16;

    const float lw0 = lift_w[c * 3 + 0], lw1 = lift_w[c * 3 + 1], lw2 = lift_w[c * 3 + 2];
    const float lb = lift_b[c];
    const float* sb = src + (size_t)b * 3 * NPIX;

    f32x4 acc[2] = {};
    for (int ks = 0; ks < 8; ++ks) {
        bf16x8 bh[2], bl[2];
        #pragma unroll
        for (int nt = 0; nt < 2; ++nt) {
            const int off = (nt * 16 + mrow) * 256 + ks * 32 + q * 8;
            bh[nt] = *(const bf16x8*)(ebhi + off);
            bl[nt] = *(const bf16x8*)(eblo + off);
        }
        const float* xp = sb + (size_t)(hbase + mrow) * NW + ks * 32 + q * 8;
        const float4 p0a = *(const float4*)(xp);
        const float4 p0b = *(const float4*)(xp + 4);
        const float4 p1a = *(const float4*)(xp + NPIX);
        const float4 p1b = *(const float4*)(xp + NPIX + 4);
        const float4 p2a = *(const float4*)(xp + 2 * NPIX);
        const float4 p2b = *(const float4*)(xp + 2 * NPIX + 4);
        float v[8];
        v[0] = lw0 * p0a.x + lw1 * p1a.x + lw2 * p2a.x + lb;
        v[1] = lw0 * p0a.y + lw1 * p1a.y + lw2 * p2a.y + lb;
        v[2] = lw0 * p0a.z + lw1 * p1a.z + lw2 * p2a.z + lb;
        v[3] = lw0 * p0a.w + lw1 * p1a.w + lw2 * p2a.w + lb;
        v[4] = lw0 * p0b.x + lw1 * p1b.x + lw2 * p2b.x + lb;
        v[5] = lw0 * p0b.y + lw1 * p1b.y + lw2 * p2b.y + lb;
        v[6] = lw0 * p0b.z + lw1 * p1b.z + lw2 * p2b.z + lb;
        v[7] = lw0 * p0b.w + lw1 * p1b.w + lw2 * p2b.w + lb;
        bf16x8 xh, xl;
        #pragma unroll
        for (int j = 0; j < 8; ++j) {
            const u16 hi = f2bf(v[j]);
            xh[j] = (short)hi;
            xl[j] = (short)f2bf(v[j] - bf2f(hi));
        }
        #pragma unroll
        for (int nt = 0; nt < 2; ++nt) {
            acc[nt] = MFMA16(xh, bh[nt], acc[nt]);
            acc[nt] = MFMA16(xh, bl[nt], acc[nt]);
            acc[nt] = MFMA16(xl, bh[nt], acc[nt]);
        }
    }

    #pragma unroll
    for (int nt = 0; nt < 2; ++nt) {
        #pragma unroll
        for (int r = 0; r < 4; ++r) {
            const int hl = wv * 16 + q * 4 + r;
            const int combo = nt * 16 + mrow;
            const float val = acc[nt][r];
            const u16 hi = f2bf(val);
            TrHi[hl][combo] = hi;
            TrLo[hl][combo] = f2bf(val - bf2f(hi));
        }
    }
    __syncthreads();

    {
        const int combo = tid >> 3, jj = tid & 7;
        bf16x8 vh, vl;
        #pragma unroll
        for (int i = 0; i < 8; ++i) {
            vh[i] = (short)TrHi[jj * 8 + i][combo];
            vl[i] = (short)TrLo[jj * 8 + i][combo];
        }
        const size_t off = (((size_t)gb * NC + c) * 32 + combo) * 256 + hq * 64 + jj * 8;
        *(bf16x8*)(yhi + off) = vh;
        *(bf16x8*)(ylo + off) = vl;
    }
}

// ---------------------------------------------------------------------------
// fwd stage 2: P[kc][wc] = sum_h EB[kc][h] * Y[wc][h]; combine quadrants.
// grid (c=32, gb), block 256.
// ---------------------------------------------------------------------------
__global__ __launch_bounds__(256) void fwd_s2(
    const u16* __restrict__ yhi,
    const u16* __restrict__ ylo,
    const u16* __restrict__ ebhi,
    const u16* __restrict__ eblo,
    float* __restrict__ zred)
{
    __shared__ float P[32][33];

    const int tid = threadIdx.x;
    const int c  = blockIdx.x;
    const int gb = blockIdx.y;
    const int wv = tid >> 6, lane = tid & 63;
    const int mrow = lane & 15, q = lane >> 4;
    const int mt2 = wv >> 1, nt2 = wv & 1;

    f32x4 p = {};
    const size_t ybase = (((size_t)gb * NC + c) * 32 + nt2 * 16 + mrow) * 256;
    for (int ks = 0; ks < 8; ++ks) {
        const int aoff = (mt2 * 16 + mrow) * 256 + ks * 32 + q * 8;
        const bf16x8 ah = *(const bf16x8*)(ebhi + aoff);
        const bf16x8 al = *(const bf16x8*)(eblo + aoff);
        const bf16x8 yh = *(const bf16x8*)(yhi + ybase + ks * 32 + q * 8);
        const bf16x8 yl = *(const bf16x8*)(ylo + ybase + ks * 32 + q * 8);
        p = MFMA16(ah, yh, p);
        p = MFMA16(ah, yl, p);
        p = MFMA16(al, yh, p);
    }
    #pragma unroll
    for (int r = 0; r < 4; ++r)
        P[mt2 * 16 + q * 4 + r][nt2 * 16 + mrow] = p[r];
    __syncthreads();

    const int k = tid >> 4, l = tid & 15;
    const float zr = P[k][l] - P[16 + k][16 + l];
    const float zi = -(P[k][16 + l] + P[16 + k][l]);
    const int idx = (gb * NC + c) * 256 + tid;
    zred[idx * 2 + 0] = zr;
    zred[idx * 2 + 1] = zi;
}

// ---------------------------------------------------------------------------
// Mode mix: grid (oc=32, mo=8, g=G); block 128 = 4 i-chunks x 32 modes.
// ---------------------------------------------------------------------------
__global__ __launch_bounds__(128) void mix_kernel(
    const float* __restrict__ zred,
    float* __restrict__ zmix,
    const float* __restrict__ wr,
    const float* __restrict__ wi,
    int o0, int n, int zgmul)
{
    __shared__ float ps[4][NB][32][2];
    const int tid = threadIdx.x;
    const int oc = blockIdx.x, mo = blockIdx.y, g = blockIdx.z;
    const int o = o0 + g, zg = zgmul * g;
    const int ichunk = tid >> 5, ml = tid & 31;
    const int mode = mo * 32 + ml;

    const float* wrb = wr + (size_t)(o * 4 + n) * NC * NC * 256;
    const float* wib = wi + (size_t)(o * 4 + n) * NC * NC * 256;

    float orr[NB] = {0.f, 0.f, 0.f, 0.f};
    float oii[NB] = {0.f, 0.f, 0.f, 0.f};

    #pragma unroll
    for (int ii = 0; ii < 8; ++ii) {
        const int i = ichunk * 8 + ii;
        const float wrv = wrb[(i * NC + oc) * 256 + mode];
        const float wiv = wib[(i * NC + oc) * 256 + mode];
        #pragma unroll
        for (int b = 0; b < NB; ++b) {
            const float2 z = *(const float2*)&zred[(((zg * NB + b) * NC + i) * 256 + mode) * 2];
            orr[b] += z.x * wrv - z.y * wiv;
            oii[b] += z.x * wiv + z.y * wrv;
        }
    }
    #pragma unroll
    for (int b = 0; b < NB; ++b) {
        ps[ichunk][b][ml][0] = orr[b];
        ps[ichunk][b][ml][1] = oii[b];
    }
    __syncthreads();

    const int b2 = tid >> 5, ml2 = tid & 31;
    float re = 0.f, im = 0.f;
    #pragma unroll
    for (int ic = 0; ic < 4; ++ic) {
        re += ps[ic][b2][ml2][0];
        im += ps[ic][b2][ml2][1];
    }
    const int oidx = ((g * NB + b2) * NC + oc) * 256 + mo * 32 + ml2;
    zmix[oidx * 2 + 0] = re;
    zmix[oidx * 2 + 1] = im;
}

// ---------------------------------------------------------------------------
// Inverse transform + bypass + GELU (+ projection if FINAL) + NEXT layer's
// row-DFT (stage 1) if PRODY. Core is the proven round-4 form; the PRODY
// section is purely appended: g row -> LDS (A-layout, split-bf16) -> 24 MFMA
// vs EB -> Y[gb][c][combo][h].
// grid: (h=256, gb=G*4), block 256.
// ---------------------------------------------------------------------------
template<bool LIFT, bool FINAL, bool PRODY>
__global__ __launch_bounds__(256) void inv_kernel(
    const float* __restrict__ zmix,
    const float* __restrict__ src,
    const float* __restrict__ byp_w,
    const float* __restrict__ byp_b,
    const float* __restrict__ lift_w,
    const float* __restrict__ lift_b,
    const float* __restrict__ proj_w,
    const float* __restrict__ proj_b,
    const u16* __restrict__ cwhi,
    const u16* __restrict__ cwlo,
    const u16* __restrict__ ebhi,
    const u16* __restrict__ eblo,
    u16* __restrict__ yhi,
    u16* __restrict__ ylo,
    float* __restrict__ dst,
    int o0, int n)
{
    __shared__ float2 tw[256];
    __shared__ u16 Thi[NC * 40], Tlo[NC * 40];
    __shared__ u16 Whi[NC * 40], Wlo[NC * 40];
    __shared__ float bbl[NC];
    __shared__ float bweffs[NC * 3];
    __shared__ u16 Ghi[PRODY ? 32 * 264 : 1];
    __shared__ u16 Glo[PRODY ? 32 * 264 : 1];

    const int tid = threadIdx.x;
    const int h = blockIdx.x;
    const int gb = blockIdx.y;
    const int g = gb >> 2, b = gb & 3;
    const int o = o0 + g;

    {
        float s, cs;
        sincospif((float)tid * (2.0f / 256.0f), &s, &cs);
        tw[tid] = make_float2(cs, s);
    }

    const float* bwp = byp_w + (size_t)(o * 4 + n) * NC * NC;
    const float* bbp = byp_b + (o * 4 + n) * NC;

    if (LIFT) {
        if (tid < 96) {
            const int oc = tid / 3, j = tid % 3;
            float s = 0.f;
            for (int ic = 0; ic < NC; ++ic) s += bwp[oc * NC + ic] * lift_w[ic * 3 + j];
            bweffs[oc * 3 + j] = s;
        } else if (tid < 128) {
            const int oc = tid - 96;
            float s = bbp[oc];
            for (int ic = 0; ic < NC; ++ic) s += bwp[oc * NC + ic] * lift_b[ic];
            bbl[oc] = s;
        }
    } else {
        if (tid < NC) bbl[tid] = bbp[tid];
    }
    __syncthreads();

    for (int idx = tid; idx < NC * NC; idx += 256) {
        const int c = idx >> 5, ic = idx & 31;
        float v;
        if (LIFT) v = (ic < 3) ? bweffs[c * 3 + ic] : 0.f;
        else      v = bwp[idx];
        const u16 hi = f2bf(v);
        Whi[c * 40 + ic] = hi;
        Wlo[c * 40 + ic] = f2bf(v - bf2f(hi));
    }

    // phase A: T[c][l] from zmix; bias folded into T[c][0]
    #pragma unroll
    for (int rep = 0; rep < 2; ++rep) {
        const int it = rep * 256 + tid;
        const int c = it >> 4, l = it & 15;
        const float sl = (l == 0 ? 1.0f : 2.0f) / 256.0f;
        const float* zp = zmix + ((size_t)(gb * NC + c) * 256 + l) * 2;
        float tr = 0.f, ti = 0.f;
        int m = 0;
        #pragma unroll
        for (int k = 0; k < NM; ++k) {
            const float2 z = *(const float2*)(zp + k * 32);
            const float2 t = tw[m];
            tr += z.x * t.x - z.y * t.y;
            ti += z.x * t.y + z.y * t.x;
            m = (m + h) & 255;
        }
        tr *= sl; ti *= sl;
        if (l == 0) tr += bbl[c];
        const u16 rh = f2bf(tr);
        Thi[c * 40 + l] = rh;
        Tlo[c * 40 + l] = f2bf(tr - bf2f(rh));
        const float nti_ = -ti;
        const u16 ih = f2bf(nti_);
        Thi[c * 40 + 16 + l] = ih;
        Tlo[c * 40 + 16 + l] = f2bf(nti_ - bf2f(ih));
    }
    __syncthreads();

    const int lane = tid & 63, wv = tid >> 6;
    const int mrow = lane & 15, q = lane >> 4;

    bf16x8 aThi[2], aTlo[2], aWhi[2], aWlo[2];
    #pragma unroll
    for (int mt = 0; mt < 2; ++mt) {
        const int ro = (mt * 16 + mrow) * 40 + 8 * q;
        aThi[mt] = *(const bf16x8*)&Thi[ro];
        aTlo[mt] = *(const bf16x8*)&Tlo[ro];
        aWhi[mt] = *(const bf16x8*)&Whi[ro];
        aWlo[mt] = *(const bf16x8*)&Wlo[ro];
    }

    float pwv[8];
    float pb = 0.f;
    if (FINAL) {
        #pragma unroll
        for (int mt = 0; mt < 2; ++mt)
            #pragma unroll
            for (int i = 0; i < 4; ++i)
                pwv[mt * 4 + i] = proj_w[mt * 16 + q * 4 + i];
        pb = proj_b[0];
    }

    const float* xb = src + (LIFT ? (size_t)b * 3 * NPIX : (size_t)gb * NC * NPIX) + h * NW;
    const int KIC = LIFT ? 3 : NC;

    for (int nti = 0; nti < 4; ++nti) {
        const int nt = wv * 4 + nti;
        const int ncol = nt * 16 + mrow;

        const bf16x8 cwh = *(const bf16x8*)(cwhi + ncol * 32 + 8 * q);
        const bf16x8 cwl = *(const bf16x8*)(cwlo + ncol * 32 + 8 * q);

        bf16x8 xh, xl;
        #pragma unroll
        for (int j = 0; j < 8; ++j) {
            const int k = 8 * q + j;
            const float v = (k < KIC) ? xb[(size_t)k * NPIX + ncol] : 0.f;
            const u16 hi = f2bf(v);
            xh[j] = (short)hi;
            xl[j] = (short)f2bf(v - bf2f(hi));
        }

        float fpart = 0.f;
        #pragma unroll
        for (int mt = 0; mt < 2; ++mt) {
            f32x4 acc = {0.f, 0.f, 0.f, 0.f};
            acc = MFMA16(aThi[mt], cwh, acc);
            acc = MFMA16(aThi[mt], cwl, acc);
            acc = MFMA16(aTlo[mt], cwh, acc);
            acc = MFMA16(aWhi[mt], xh, acc);
            acc = MFMA16(aWhi[mt], xl, acc);
            acc = MFMA16(aWlo[mt], xh, acc);
            if (FINAL) {
                #pragma unroll
                for (int i = 0; i < 4; ++i)
                    fpart += gelu_fast(acc[i]) * pwv[mt * 4 + i];
            } else {
                #pragma unroll
                for (int i = 0; i < 4; ++i) {
                    const int c = mt * 16 + q * 4 + i;
                    const float gl = gelu_fast(acc[i]);
                    dst[((size_t)gb * NC + c) * NPIX + h * NW + ncol] = gl;
                    if (PRODY) {
                        const u16 hi = f2bf(gl);
                        Ghi[c * 264 + ncol] = hi;
                        Glo[c * 264 + ncol] = f2bf(gl - bf2f(hi));
                    }
                }
            }
        }
        if (FINAL) {
            fpart += __shfl_xor(fpart, 16);
            fpart += __shfl_xor(fpart, 32);
            if (q == 0) {
                dst[(((size_t)b * 4 + o) * NH + h) * NW + nt * 16 + mrow] = fpart + pb;
            }
        }
    }

    // ---- appended: next layer's row-DFT for this (h, gb) ----
    if (PRODY) {
        __syncthreads();
        const int mt1 = wv >> 1, nt1 = wv & 1;   // 4 waves = 2x2 tiles of 32x32
        f32x4 yacc = {};
        for (int ks = 0; ks < 8; ++ks) {
            const int ao = (mt1 * 16 + mrow) * 264 + ks * 32 + q * 8;
            const bf16x8 gh = *(const bf16x8*)&Ghi[ao];
            const bf16x8 gl = *(const bf16x8*)&Glo[ao];
            const int bo = (nt1 * 16 + mrow) * 256 + ks * 32 + q * 8;
            const bf16x8 bh = *(const bf16x8*)(ebhi + bo);
            const bf16x8 bl = *(const bf16x8*)(eblo + bo);
            yacc = MFMA16(gh, bh, yacc);
            yacc = MFMA16(gh, bl, yacc);
            yacc = MFMA16(gl, bh, yacc);
        }
        #pragma unroll
        for (int r = 0; r < 4; ++r) {
            const int c = mt1 * 16 + q * 4 + r;
            const int combo = nt1 * 16 + mrow;
            const size_t off = (((size_t)gb * NC + c) * 32 + combo) * 256 + h;
            const float val = yacc[r];
            const u16 hi = f2bf(val);
            yhi[off] = hi;
            ylo[off] = f2bf(val - bf2f(hi));
        }
    }
}

// ---------------------------------------------------------------------------
extern "C" void kernel_launch(void* const* d_in, const int* in_sizes, int n_in,
                              void* d_out, int out_size, void* d_ws, size_t ws_size,
                              hipStream_t stream)
{
    const float* x      = (const float*)d_in[0];
    const float* lift_w = (const float*)d_in[1];
    const float* lift_b = (const float*)d_in[2];
    const float* wr     = (const float*)d_in[3];
    const float* wi     = (const float*)d_in[4];
    const float* byp_w  = (const float*)d_in[5];
    const float* byp_b  = (const float*)d_in[6];
    const float* proj_w = (const float*)d_in[7];
    const float* proj_b = (const float*)d_in[8];
    float* out = (float*)d_out;
    float* ws  = (float*)d_ws;

    // ws: [cw/eb tables: 4 x 8192 u16 = 16384 floats] [yhi|ylo] [bufA|bufB] [zred|zmix]
    u16* cwhi = (u16*)ws;
    u16* cwlo = cwhi + 8192;
    u16* ebhi = cwlo + 8192;
    u16* eblo = ebhi + 8192;
    float* base = ws + 16384;

    int G = 2;
    while (G > 1) {
        const size_t yfl = ((size_t)G * NB * NC * 32 * 256 * 2 * 2) / 4;  // floats for yhi+ylo
        const size_t need = (16384 + yfl + (size_t)2 * G * NP + (size_t)2 * G * ZG) * sizeof(float);
        if (need <= ws_size) break;
        G >>= 1;
    }

    const size_t ycnt = (size_t)G * NB * NC * 32 * 256;   // u16 elements per y array
    u16* yhi = (u16*)base;
    u16* ylo = yhi + ycnt;
    float* bufA = base + (ycnt * 2 * 2) / 4;
    float* bufB = bufA + (size_t)G * NP;
    float* zred = bufB + (size_t)G * NP;
    float* zmix = zred + (size_t)G * ZG;

    tab_prep<<<64, 256, 0, stream>>>(cwhi, cwlo, ebhi, eblo);

    for (int o0 = 0; o0 < 4; o0 += G) {
        // lift spectrum is g-independent: compute its Y once over (c, b, hq)
        fwd_s1_lift<<<dim3(NC, NB, 4), 256, 0, stream>>>(x, lift_w, lift_b, ebhi, eblo, yhi, ylo);

        const float* rd = nullptr;
        float* wrbuf = bufA;
        for (int n = 0; n < 4; ++n) {
            const bool lift = (n == 0);
            const bool fin  = (n == 3);
            const float* src = lift ? x : rd;
            const int ngb = lift ? NB : G * NB;

            fwd_s2<<<dim3(NC, ngb), 256, 0, stream>>>(yhi, ylo, ebhi, eblo, zred);

            mix_kernel<<<dim3(NC, 8, G), 128, 0, stream>>>(zred, zmix, wr, wi, o0, n, lift ? 0 : 1);

            dim3 igrid(NH, G * NB);
            if (fin) {
                inv_kernel<false, true, false><<<igrid, 256, 0, stream>>>(
                    zmix, src, byp_w, byp_b, lift_w, lift_b, proj_w, proj_b,
                    cwhi, cwlo, ebhi, eblo, yhi, ylo, out, o0, n);
            } else if (lift) {
                inv_kernel<true, false, true><<<igrid, 256, 0, stream>>>(
                    zmix, src, byp_w, byp_b, lift_w, lift_b, proj_w, proj_b,
                    cwhi, cwlo, ebhi, eblo, yhi, ylo, wrbuf, o0, n);
            } else {
                inv_kernel<false, false, true><<<igrid, 256, 0, stream>>>(
                    zmix, src, byp_w, byp_b, lift_w, lift_b, proj_w, proj_b,
                    cwhi, cwlo, ebhi, eblo, yhi, ylo, wrbuf, o0, n);
            }
            rd = wrbuf;
            wrbuf = (wrbuf == bufA) ? bufB : bufA;
        }
    }
}

// Round 8
// 586.477 us; speedup vs baseline: 1.0923x; 1.0923x over previous
//
#include <hip/hip_runtime.h>

#define NB 4      // batch
#define NC 32     // width (channels)
#define NH 256
#define NW 256
#define NM 16     // modes per dim
constexpr int NPIX = NH * NW;                 // 65536
constexpr int NP = NB * NC * NPIX;            // floats per per-o tensor
constexpr int ZG = NB * NC * NM * NM * 2;     // floats per g for zmix

typedef short bf16x8 __attribute__((ext_vector_type(8)));
typedef float f32x4  __attribute__((ext_vector_type(4)));
typedef unsigned short u16;

#define MFMA16(a, b, c) __builtin_amdgcn_mfma_f32_16x16x32_bf16(a, b, c, 0, 0, 0)

__device__ __forceinline__ u16 f2bf(float f) {
    unsigned u = __float_as_uint(f);
    u += 0x7FFFu + ((u >> 16) & 1u);
    return (u16)(u >> 16);
}
__device__ __forceinline__ float bf2f(u16 h) {
    return __uint_as_float(((unsigned)h) << 16);
}

// fast erf (A&S 7.1.26, |err| <= 1.5e-7) based exact-GELU
__device__ __forceinline__ float gelu_fast(float v) {
    const float ax = fabsf(v) * 0.70710678118654752f;
    const float t = __builtin_amdgcn_rcpf(1.0f + 0.3275911f * ax);
    const float y = t * (0.254829592f + t * (-0.284496736f + t * (1.421413741f +
                    t * (-1.453152027f + t * 1.061405429f))));
    const float e = __expf(-ax * ax);
    float er = 1.0f - y * e;
    er = copysignf(er, v);
    return 0.5f * v * (1.0f + er);
}

// ---------------------------------------------------------------------------
// Table prep: cw (inv B-operand, [n=256][k=32]) and eb (fwd DFT matrix,
// [row=32][w=256], scaled 1/16; applied twice -> 1/256 ortho norm).
// ---------------------------------------------------------------------------
__global__ __launch_bounds__(256) void tab_prep(
    u16* __restrict__ cwhi, u16* __restrict__ cwlo,
    u16* __restrict__ ebhi, u16* __restrict__ eblo)
{
    const int id = blockIdx.x * 256 + threadIdx.x;   // 0..16383
    if (id < 8192) {
        const int nn = id >> 5, k = id & 31;
        const int m = ((k & 15) * nn) & 255;
        float s, c;
        sincospif((float)m * (2.0f / 256.0f), &s, &c);
        const float v = (k < 16) ? c : s;
        const u16 hi = f2bf(v);
        cwhi[id] = hi;
        cwlo[id] = f2bf(v - bf2f(hi));
    } else {
        const int id2 = id - 8192;
        const int row = id2 >> 8, w = id2 & 255;
        const int m = ((row & 15) * w) & 255;
        float s, c;
        sincospif((float)m * (2.0f / 256.0f), &s, &c);
        const float v = 0.0625f * ((row < 16) ? c : s);
        const u16 hi = f2bf(v);
        ebhi[id2] = hi;
        eblo[id2] = f2bf(v - bf2f(hi));
    }
}

// ---------------------------------------------------------------------------
// fwd: both DFT stages for a 64-row h-chunk; partial Z to zpart[hq][gb][c][mode].
// grid (c=32, gb=ngb, hq=4), block 256 (4 waves; wave wv owns rows
// hq*64+wv*16 .. +16). Stage 1 per-wave identical to verified round-6 s1;
// stage 2 sums this block's 64 h with EB (global) x Y (LDS); quadrant-combine
// then a coalesced 2KB fp32 write. Deterministic (no atomics); mix reduces hq.
// ---------------------------------------------------------------------------
template<bool LIFT>
__global__ __launch_bounds__(256) void fwd_kernel(
    const float* __restrict__ src,      // LIFT ? x[B,3,H,W] : xb[G,B,C,H,W]
    const float* __restrict__ lift_w,
    const float* __restrict__ lift_b,
    const u16* __restrict__ ebhi,
    const u16* __restrict__ eblo,
    float* __restrict__ zpart)          // [hq][gb][c][mode][2]
{
    __shared__ u16 Yhi[32][72], Ylo[32][72];   // [combo][hl], stride 72 (16B-aligned)
    __shared__ float P[32][33];

    const int tid = threadIdx.x;
    const int c  = blockIdx.x;
    const int gb = blockIdx.y;          // LIFT: gb == b
    const int hq = blockIdx.z;
    const int ngb = gridDim.y;
    const int b  = gb & 3;
    const int wv = tid >> 6, lane = tid & 63;
    const int mrow = lane & 15, q = lane >> 4;
    const int hbase = hq * 64 + wv * 16;

    float lw0 = 0.f, lw1 = 0.f, lw2 = 0.f, lb = 0.f;
    const float* sb;
    if (LIFT) {
        lw0 = lift_w[c * 3 + 0]; lw1 = lift_w[c * 3 + 1]; lw2 = lift_w[c * 3 + 2];
        lb = lift_b[c];
        sb = src + (size_t)b * 3 * NPIX;
    } else {
        sb = src + ((size_t)gb * NC + c) * NPIX;
    }

    // ---- stage 1: Y[hl, 32 combos] for this block's 64 rows ----
    f32x4 acc[2] = {};
    for (int ks = 0; ks < 8; ++ks) {
        bf16x8 bh[2], bl[2];
        #pragma unroll
        for (int nt = 0; nt < 2; ++nt) {
            const int off = (nt * 16 + mrow) * 256 + ks * 32 + q * 8;
            bh[nt] = *(const bf16x8*)(ebhi + off);
            bl[nt] = *(const bf16x8*)(eblo + off);
        }
        const float* xp = sb + (size_t)(hbase + mrow) * NW + ks * 32 + q * 8;
        float v[8];
        if (LIFT) {
            const float4 p0a = *(const float4*)(xp);
            const float4 p0b = *(const float4*)(xp + 4);
            const float4 p1a = *(const float4*)(xp + NPIX);
            const float4 p1b = *(const float4*)(xp + NPIX + 4);
            const float4 p2a = *(const float4*)(xp + 2 * NPIX);
            const float4 p2b = *(const float4*)(xp + 2 * NPIX + 4);
            v[0] = lw0 * p0a.x + lw1 * p1a.x + lw2 * p2a.x + lb;
            v[1] = lw0 * p0a.y + lw1 * p1a.y + lw2 * p2a.y + lb;
            v[2] = lw0 * p0a.z + lw1 * p1a.z + lw2 * p2a.z + lb;
            v[3] = lw0 * p0a.w + lw1 * p1a.w + lw2 * p2a.w + lb;
            v[4] = lw0 * p0b.x + lw1 * p1b.x + lw2 * p2b.x + lb;
            v[5] = lw0 * p0b.y + lw1 * p1b.y + lw2 * p2b.y + lb;
            v[6] = lw0 * p0b.z + lw1 * p1b.z + lw2 * p2b.z + lb;
            v[7] = lw0 * p0b.w + lw1 * p1b.w + lw2 * p2b.w + lb;
        } else {
            const float4 pa = *(const float4*)(xp);
            const float4 pb = *(const float4*)(xp + 4);
            v[0] = pa.x; v[1] = pa.y; v[2] = pa.z; v[3] = pa.w;
            v[4] = pb.x; v[5] = pb.y; v[6] = pb.z; v[7] = pb.w;
        }
        bf16x8 xh, xl;
        #pragma unroll
        for (int j = 0; j < 8; ++j) {
            const u16 hi = f2bf(v[j]);
            xh[j] = (short)hi;
            xl[j] = (short)f2bf(v[j] - bf2f(hi));
        }
        #pragma unroll
        for (int nt = 0; nt < 2; ++nt) {
            acc[nt] = MFMA16(xh, bh[nt], acc[nt]);
            acc[nt] = MFMA16(xh, bl[nt], acc[nt]);
            acc[nt] = MFMA16(xl, bh[nt], acc[nt]);
        }
    }

    // C-layout scatter into LDS: acc[nt][r] at (hl = wv*16 + q*4 + r, combo = nt*16 + mrow)
    #pragma unroll
    for (int nt = 0; nt < 2; ++nt) {
        #pragma unroll
        for (int r = 0; r < 4; ++r) {
            const int hl = wv * 16 + q * 4 + r;
            const int combo = nt * 16 + mrow;
            const float val = acc[nt][r];
            const u16 hi = f2bf(val);
            Yhi[combo][hl] = hi;
            Ylo[combo][hl] = f2bf(val - bf2f(hi));
        }
    }
    __syncthreads();

    // ---- stage 2: partial P[kc][wc] over this block's 64 h ----
    const int mt2 = wv >> 1, nt2 = wv & 1;
    f32x4 p = {};
    #pragma unroll
    for (int ks = 0; ks < 2; ++ks) {
        const int aoff = (mt2 * 16 + mrow) * 256 + hq * 64 + ks * 32 + q * 8;
        const bf16x8 ah = *(const bf16x8*)(ebhi + aoff);
        const bf16x8 al = *(const bf16x8*)(eblo + aoff);
        const bf16x8 yh = *(const bf16x8*)&Yhi[nt2 * 16 + mrow][ks * 32 + q * 8];
        const bf16x8 yl = *(const bf16x8*)&Ylo[nt2 * 16 + mrow][ks * 32 + q * 8];
        p = MFMA16(ah, yh, p);
        p = MFMA16(ah, yl, p);
        p = MFMA16(al, yh, p);
    }
    #pragma unroll
    for (int r = 0; r < 4; ++r)
        P[mt2 * 16 + q * 4 + r][nt2 * 16 + mrow] = p[r];
    __syncthreads();

    // ---- combine + coalesced partial store ----
    const int k = tid >> 4, l = tid & 15;
    const float zr = P[k][l] - P[16 + k][16 + l];
    const float zi = -(P[k][16 + l] + P[16 + k][l]);
    const size_t idx = (((size_t)hq * ngb + gb) * NC + c) * 256 + tid;
    zpart[idx * 2 + 0] = zr;
    zpart[idx * 2 + 1] = zi;
}

// ---------------------------------------------------------------------------
// Mode mix: reduce 4 hq-partials + complex channel matmul.
// grid (oc=32, mo=8, g=G); block 128 = 4 i-chunks x 32 modes.
// ---------------------------------------------------------------------------
__global__ __launch_bounds__(128) void mix_kernel(
    const float* __restrict__ zpart,    // [hq][ngb][c][mode][2]
    float* __restrict__ zmix,
    const float* __restrict__ wr,
    const float* __restrict__ wi,
    int o0, int n, int zgmul, int ngb)
{
    __shared__ float ps[4][NB][32][2];
    const int tid = threadIdx.x;
    const int oc = blockIdx.x, mo = blockIdx.y, g = blockIdx.z;
    const int o = o0 + g, zg = zgmul * g;
    const int ichunk = tid >> 5, ml = tid & 31;
    const int mode = mo * 32 + ml;
    const size_t hqs = (size_t)ngb * NC * 512;   // float stride between hq slabs

    const float* wrb = wr + (size_t)(o * 4 + n) * NC * NC * 256;
    const float* wib = wi + (size_t)(o * 4 + n) * NC * NC * 256;

    float orr[NB] = {0.f, 0.f, 0.f, 0.f};
    float oii[NB] = {0.f, 0.f, 0.f, 0.f};

    #pragma unroll
    for (int ii = 0; ii < 8; ++ii) {
        const int i = ichunk * 8 + ii;
        const float wrv = wrb[(i * NC + oc) * 256 + mode];
        const float wiv = wib[(i * NC + oc) * 256 + mode];
        #pragma unroll
        for (int b = 0; b < NB; ++b) {
            const size_t zi0 = ((size_t)(zg * NB + b) * NC + i) * 512 + mode * 2;
            float zx = 0.f, zy = 0.f;
            #pragma unroll
            for (int hq = 0; hq < 4; ++hq) {
                const float2 z = *(const float2*)&zpart[hq * hqs + zi0];
                zx += z.x; zy += z.y;
            }
            orr[b] += zx * wrv - zy * wiv;
            oii[b] += zx * wiv + zy * wrv;
        }
    }
    #pragma unroll
    for (int b = 0; b < NB; ++b) {
        ps[ichunk][b][ml][0] = orr[b];
        ps[ichunk][b][ml][1] = oii[b];
    }
    __syncthreads();

    const int b2 = tid >> 5, ml2 = tid & 31;
    float re = 0.f, im = 0.f;
    #pragma unroll
    for (int ic = 0; ic < 4; ++ic) {
        re += ps[ic][b2][ml2][0];
        im += ps[ic][b2][ml2][1];
    }
    const int oidx = ((g * NB + b2) * NC + oc) * 256 + mo * 32 + ml2;
    zmix[oidx * 2 + 0] = re;
    zmix[oidx * 2 + 1] = im;
}

// ---------------------------------------------------------------------------
// Inverse transform + bypass + GELU (+ fused projection), split-bf16 MFMA.
// EXACT round-4 form (ping-pong src/dst, __restrict__, loads in nti loop).
// grid: (h=256, gb=G*4), block 256.
// ---------------------------------------------------------------------------
template<bool LIFT, bool FINAL>
__global__ __launch_bounds__(256) void inv_kernel(
    const float* __restrict__ zmix,
    const float* __restrict__ src,
    const float* __restrict__ byp_w,
    const float* __restrict__ byp_b,
    const float* __restrict__ lift_w,
    const float* __restrict__ lift_b,
    const float* __restrict__ proj_w,
    const float* __restrict__ proj_b,
    const u16* __restrict__ cwhi,
    const u16* __restrict__ cwlo,
    float* __restrict__ dst,
    int o0, int n)
{
    __shared__ float2 tw[256];
    __shared__ u16 Thi[NC * 40], Tlo[NC * 40];
    __shared__ u16 Whi[NC * 40], Wlo[NC * 40];
    __shared__ float bbl[NC];
    __shared__ float bweffs[NC * 3];

    const int tid = threadIdx.x;
    const int h = blockIdx.x;
    const int gb = blockIdx.y;
    const int g = gb >> 2, b = gb & 3;
    const int o = o0 + g;

    {
        float s, cs;
        sincospif((float)tid * (2.0f / 256.0f), &s, &cs);
        tw[tid] = make_float2(cs, s);
    }

    const float* bwp = byp_w + (size_t)(o * 4 + n) * NC * NC;
    const float* bbp = byp_b + (o * 4 + n) * NC;

    if (LIFT) {
        if (tid < 96) {
            const int oc = tid / 3, j = tid % 3;
            float s = 0.f;
            for (int ic = 0; ic < NC; ++ic) s += bwp[oc * NC + ic] * lift_w[ic * 3 + j];
            bweffs[oc * 3 + j] = s;
        } else if (tid < 128) {
            const int oc = tid - 96;
            float s = bbp[oc];
            for (int ic = 0; ic < NC; ++ic) s += bwp[oc * NC + ic] * lift_b[ic];
            bbl[oc] = s;
        }
    } else {
        if (tid < NC) bbl[tid] = bbp[tid];
    }
    __syncthreads();

    for (int idx = tid; idx < NC * NC; idx += 256) {
        const int c = idx >> 5, ic = idx & 31;
        float v;
        if (LIFT) v = (ic < 3) ? bweffs[c * 3 + ic] : 0.f;
        else      v = bwp[idx];
        const u16 hi = f2bf(v);
        Whi[c * 40 + ic] = hi;
        Wlo[c * 40 + ic] = f2bf(v - bf2f(hi));
    }

    // phase A: T[c][l] from zmix; bias folded into T[c][0]
    #pragma unroll
    for (int rep = 0; rep < 2; ++rep) {
        const int it = rep * 256 + tid;
        const int c = it >> 4, l = it & 15;
        const float sl = (l == 0 ? 1.0f : 2.0f) / 256.0f;
        const float* zp = zmix + ((size_t)(gb * NC + c) * 256 + l) * 2;
        float tr = 0.f, ti = 0.f;
        int m = 0;
        #pragma unroll
        for (int k = 0; k < NM; ++k) {
            const float2 z = *(const float2*)(zp + k * 32);
            const float2 t = tw[m];
            tr += z.x * t.x - z.y * t.y;
            ti += z.x * t.y + z.y * t.x;
            m = (m + h) & 255;
        }
        tr *= sl; ti *= sl;
        if (l == 0) tr += bbl[c];
        const u16 rh = f2bf(tr);
        Thi[c * 40 + l] = rh;
        Tlo[c * 40 + l] = f2bf(tr - bf2f(rh));
        const float nti_ = -ti;
        const u16 ih = f2bf(nti_);
        Thi[c * 40 + 16 + l] = ih;
        Tlo[c * 40 + 16 + l] = f2bf(nti_ - bf2f(ih));
    }
    __syncthreads();

    const int lane = tid & 63, wv = tid >> 6;
    const int mrow = lane & 15, q = lane >> 4;

    bf16x8 aThi[2], aTlo[2], aWhi[2], aWlo[2];
    #pragma unroll
    for (int mt = 0; mt < 2; ++mt) {
        const int ro = (mt * 16 + mrow) * 40 + 8 * q;
        aThi[mt] = *(const bf16x8*)&Thi[ro];
        aTlo[mt] = *(const bf16x8*)&Tlo[ro];
        aWhi[mt] = *(const bf16x8*)&Whi[ro];
        aWlo[mt] = *(const bf16x8*)&Wlo[ro];
    }

    float pwv[8];
    float pb = 0.f;
    if (FINAL) {
        #pragma unroll
        for (int mt = 0; mt < 2; ++mt)
            #pragma unroll
            for (int i = 0; i < 4; ++i)
                pwv[mt * 4 + i] = proj_w[mt * 16 + q * 4 + i];
        pb = proj_b[0];
    }

    const float* xb = src + (LIFT ? (size_t)b * 3 * NPIX : (size_t)gb * NC * NPIX) + h * NW;
    const int KIC = LIFT ? 3 : NC;

    for (int nti = 0; nti < 4; ++nti) {
        const int nt = wv * 4 + nti;
        const int ncol = nt * 16 + mrow;

        const bf16x8 cwh = *(const bf16x8*)(cwhi + ncol * 32 + 8 * q);
        const bf16x8 cwl = *(const bf16x8*)(cwlo + ncol * 32 + 8 * q);

        bf16x8 xh, xl;
        #pragma unroll
        for (int j = 0; j < 8; ++j) {
            const int k = 8 * q + j;
            const float v = (k < KIC) ? xb[(size_t)k * NPIX + ncol] : 0.f;
            const u16 hi = f2bf(v);
            xh[j] = (short)hi;
            xl[j] = (short)f2bf(v - bf2f(hi));
        }

        float fpart = 0.f;
        #pragma unroll
        for (int mt = 0; mt < 2; ++mt) {
            f32x4 acc = {0.f, 0.f, 0.f, 0.f};
            acc = MFMA16(aThi[mt], cwh, acc);
            acc = MFMA16(aThi[mt], cwl, acc);
            acc = MFMA16(aTlo[mt], cwh, acc);
            acc = MFMA16(aWhi[mt], xh, acc);
            acc = MFMA16(aWhi[mt], xl, acc);
            acc = MFMA16(aWlo[mt], xh, acc);
            if (FINAL) {
                #pragma unroll
                for (int i = 0; i < 4; ++i)
                    fpart += gelu_fast(acc[i]) * pwv[mt * 4 + i];
            } else {
                #pragma unroll
                for (int i = 0; i < 4; ++i) {
                    const int c = mt * 16 + q * 4 + i;
                    dst[((size_t)gb * NC + c) * NPIX + h * NW + ncol] = gelu_fast(acc[i]);
                }
            }
        }
        if (FINAL) {
            fpart += __shfl_xor(fpart, 16);
            fpart += __shfl_xor(fpart, 32);
            if (q == 0) {
                dst[(((size_t)b * 4 + o) * NH + h) * NW + nt * 16 + mrow] = fpart + pb;
            }
        }
    }
}

// ---------------------------------------------------------------------------
extern "C" void kernel_launch(void* const* d_in, const int* in_sizes, int n_in,
                              void* d_out, int out_size, void* d_ws, size_t ws_size,
                              hipStream_t stream)
{
    const float* x      = (const float*)d_in[0];
    const float* lift_w = (const float*)d_in[1];
    const float* lift_b = (const float*)d_in[2];
    const float* wr     = (const float*)d_in[3];
    const float* wi     = (const float*)d_in[4];
    const float* byp_w  = (const float*)d_in[5];
    const float* byp_b  = (const float*)d_in[6];
    const float* proj_w = (const float*)d_in[7];
    const float* proj_b = (const float*)d_in[8];
    float* out = (float*)d_out;
    float* ws  = (float*)d_ws;

    // ws: [cw/eb tables 16384 fl][zplift][zpart][zmix][bufA][bufB]
    u16* cwhi = (u16*)ws;
    u16* cwlo = cwhi + 8192;
    u16* ebhi = cwlo + 8192;
    u16* eblo = ebhi + 8192;
    float* base = ws + 16384;

    int G = 2;
    const size_t ZPL = (size_t)4 * NB * NC * 512;          // zplift floats (ngb=4)
    while (G > 1) {
        const size_t zp = (size_t)4 * (G * NB) * NC * 512; // zpart floats
        const size_t need = (16384 + ZPL + zp + (size_t)G * ZG + (size_t)2 * G * NP) * sizeof(float);
        if (need <= ws_size) break;
        G >>= 1;
    }

    float* zplift = base;
    float* zpart  = zplift + ZPL;
    float* zmix   = zpart + (size_t)4 * (G * NB) * NC * 512;
    float* bufA   = zmix + (size_t)G * ZG;
    float* bufB   = bufA + (size_t)G * NP;

    tab_prep<<<64, 256, 0, stream>>>(cwhi, cwlo, ebhi, eblo);

    // lift spectrum is o-independent: compute its partials ONCE
    fwd_kernel<true><<<dim3(NC, NB, 4), 256, 0, stream>>>(x, lift_w, lift_b, ebhi, eblo, zplift);

    for (int o0 = 0; o0 < 4; o0 += G) {
        const float* rd = nullptr;
        float* wrbuf = bufA;
        for (int n = 0; n < 4; ++n) {
            const bool lift = (n == 0);
            const bool fin  = (n == 3);
            const float* src = lift ? x : rd;

            if (!lift)
                fwd_kernel<false><<<dim3(NC, G * NB, 4), 256, 0, stream>>>(src, lift_w, lift_b, ebhi, eblo, zpart);

            mix_kernel<<<dim3(NC, 8, G), 128, 0, stream>>>(
                lift ? zplift : zpart, zmix, wr, wi, o0, n, lift ? 0 : 1, lift ? NB : G * NB);

            dim3 igrid(NH, G * NB);
            if (fin) {
                inv_kernel<false, true><<<igrid, 256, 0, stream>>>(
                    zmix, src, byp_w, byp_b, lift_w, lift_b, proj_w, proj_b, cwhi, cwlo, out, o0, n);
            } else if (lift) {
                inv_kernel<true, false><<<igrid, 256, 0, stream>>>(
                    zmix, src, byp_w, byp_b, lift_w, lift_b, proj_w, proj_b, cwhi, cwlo, wrbuf, o0, n);
            } else {
                inv_kernel<false, false><<<igrid, 256, 0, stream>>>(
                    zmix, src, byp_w, byp_b, lift_w, lift_b, proj_w, proj_b, cwhi, cwlo, wrbuf, o0, n);
            }
            rd = wrbuf;
            wrbuf = (wrbuf == bufA) ? bufB : bufA;
        }
    }
}

// Round 9
// 531.040 us; speedup vs baseline: 1.2063x; 1.1044x over previous
//
#include <hip/hip_runtime.h>

#define NB 4      // batch
#define NC 32     // width (channels)
#define NH 256
#define NW 256
#define NM 16     // modes per dim
constexpr int NPIX = NH * NW;                 // 65536
constexpr int NP = NB * NC * NPIX;            // elements per per-o tensor (u32-packed)
constexpr int ZG = NB * NC * NM * NM * 2;     // floats per g for zred/zmix

typedef short bf16x8 __attribute__((ext_vector_type(8)));
typedef float f32x4  __attribute__((ext_vector_type(4)));
typedef unsigned short u16;
typedef unsigned int u32;

#define MFMA16(a, b, c) __builtin_amdgcn_mfma_f32_16x16x32_bf16(a, b, c, 0, 0, 0)

__device__ __forceinline__ u16 f2bf(float f) {
    unsigned u = __float_as_uint(f);
    u += 0x7FFFu + ((u >> 16) & 1u);
    return (u16)(u >> 16);
}
__device__ __forceinline__ float bf2f(u16 h) {
    return __uint_as_float(((unsigned)h) << 16);
}
// pack fp32 -> (hi bf16) | (lo bf16 << 16); downstream consumers use exactly hi+lo
__device__ __forceinline__ u32 packsplit(float f) {
    const u16 hi = f2bf(f);
    const u16 lo = f2bf(f - bf2f(hi));
    return (u32)hi | ((u32)lo << 16);
}

// fast erf (A&S 7.1.26, |err| <= 1.5e-7) based exact-GELU
__device__ __forceinline__ float gelu_fast(float v) {
    const float ax = fabsf(v) * 0.70710678118654752f;
    const float t = __builtin_amdgcn_rcpf(1.0f + 0.3275911f * ax);
    const float y = t * (0.254829592f + t * (-0.284496736f + t * (1.421413741f +
                    t * (-1.453152027f + t * 1.061405429f))));
    const float e = __expf(-ax * ax);
    float er = 1.0f - y * e;
    er = copysignf(er, v);
    return 0.5f * v * (1.0f + er);
}

// ---------------------------------------------------------------------------
// Table prep: cw (inv B-operand, [n=256][k=32]) and eb (fwd DFT matrix,
// [row=32][w=256], scaled 1/16; applied twice -> 1/256 ortho norm).
// ---------------------------------------------------------------------------
__global__ __launch_bounds__(256) void tab_prep(
    u16* __restrict__ cwhi, u16* __restrict__ cwlo,
    u16* __restrict__ ebhi, u16* __restrict__ eblo)
{
    const int id = blockIdx.x * 256 + threadIdx.x;   // 0..16383
    if (id < 8192) {
        const int nn = id >> 5, k = id & 31;
        const int m = ((k & 15) * nn) & 255;
        float s, c;
        sincospif((float)m * (2.0f / 256.0f), &s, &c);
        const float v = (k < 16) ? c : s;
        const u16 hi = f2bf(v);
        cwhi[id] = hi;
        cwlo[id] = f2bf(v - bf2f(hi));
    } else {
        const int id2 = id - 8192;
        const int row = id2 >> 8, w = id2 & 255;
        const int m = ((row & 15) * w) & 255;
        float s, c;
        sincospif((float)m * (2.0f / 256.0f), &s, &c);
        const float v = 0.0625f * ((row < 16) ? c : s);
        const u16 hi = f2bf(v);
        ebhi[id2] = hi;
        eblo[id2] = f2bf(v - bf2f(hi));
    }
}

// ---------------------------------------------------------------------------
// Forward truncated DFT (round-4 monolithic form), split-bf16 MFMA, 2-stage.
// LIFT: reads fp32 x + lift conv. !LIFT: reads PACKED xb (u32 = hi|lo<<16),
// fragments rebuilt with shifts (no float->bf16 conversion).
// grid: (32, LIFT ? 4 : G*4), block 512.
// ---------------------------------------------------------------------------
template<bool LIFT>
__global__ __launch_bounds__(512) void fwd_kernel(
    const void* __restrict__ srcv,      // LIFT ? float x[B,3,H,W] : u32 xb[G,B,C,H,W]
    const float* __restrict__ lift_w,
    const float* __restrict__ lift_b,
    const u16* __restrict__ ebhi,
    const u16* __restrict__ eblo,
    float* __restrict__ zred)
{
    __shared__ u16 Yhi[32 * 260], Ylo[32 * 260];   // [combo][h], pad 260
    __shared__ float P[32][33];

    const int tid = threadIdx.x;
    const int c  = blockIdx.x;
    const int gb = blockIdx.y;          // LIFT: gb == b
    const int b  = gb & 3;
    const int wv = tid >> 6, lane = tid & 63;
    const int mrow = lane & 15, q = lane >> 4;

    float lw0 = 0.f, lw1 = 0.f, lw2 = 0.f, lb = 0.f;
    const float* sbf = nullptr;
    const u32* sbp = nullptr;
    if (LIFT) {
        lw0 = lift_w[c * 3 + 0]; lw1 = lift_w[c * 3 + 1]; lw2 = lift_w[c * 3 + 2];
        lb = lift_b[c];
        sbf = (const float*)srcv + (size_t)b * 3 * NPIX;
    } else {
        sbp = (const u32*)srcv + ((size_t)gb * NC + c) * NPIX;
    }

    // ---- stage 1: Y[h,32] = X[h,:] * EB^T ----
    f32x4 acc[2][2] = {};
    for (int ks = 0; ks < 8; ++ks) {
        bf16x8 bh[2], bl[2];
        #pragma unroll
        for (int nt = 0; nt < 2; ++nt) {
            const int off = (nt * 16 + mrow) * 256 + ks * 32 + q * 8;
            bh[nt] = *(const bf16x8*)(ebhi + off);
            bl[nt] = *(const bf16x8*)(eblo + off);
        }
        #pragma unroll
        for (int mt = 0; mt < 2; ++mt) {
            const int h = wv * 32 + mt * 16 + mrow;
            bf16x8 xh, xl;
            if (LIFT) {
                const float* xp = sbf + (size_t)h * NW + ks * 32 + q * 8;
                const float4 p0a = *(const float4*)(xp);
                const float4 p0b = *(const float4*)(xp + 4);
                const float4 p1a = *(const float4*)(xp + NPIX);
                const float4 p1b = *(const float4*)(xp + NPIX + 4);
                const float4 p2a = *(const float4*)(xp + 2 * NPIX);
                const float4 p2b = *(const float4*)(xp + 2 * NPIX + 4);
                float v[8];
                v[0] = lw0 * p0a.x + lw1 * p1a.x + lw2 * p2a.x + lb;
                v[1] = lw0 * p0a.y + lw1 * p1a.y + lw2 * p2a.y + lb;
                v[2] = lw0 * p0a.z + lw1 * p1a.z + lw2 * p2a.z + lb;
                v[3] = lw0 * p0a.w + lw1 * p1a.w + lw2 * p2a.w + lb;
                v[4] = lw0 * p0b.x + lw1 * p1b.x + lw2 * p2b.x + lb;
                v[5] = lw0 * p0b.y + lw1 * p1b.y + lw2 * p2b.y + lb;
                v[6] = lw0 * p0b.z + lw1 * p1b.z + lw2 * p2b.z + lb;
                v[7] = lw0 * p0b.w + lw1 * p1b.w + lw2 * p2b.w + lb;
                #pragma unroll
                for (int j = 0; j < 8; ++j) {
                    const u16 hi = f2bf(v[j]);
                    xh[j] = (short)hi;
                    xl[j] = (short)f2bf(v[j] - bf2f(hi));
                }
            } else {
                const u32* xp = sbp + (size_t)h * NW + ks * 32 + q * 8;
                const uint4 pa = *(const uint4*)(xp);
                const uint4 pb = *(const uint4*)(xp + 4);
                u32 p[8] = {pa.x, pa.y, pa.z, pa.w, pb.x, pb.y, pb.z, pb.w};
                union { uint4 u; bf16x8 v; } ch, cl;
                ch.u.x = (p[0] & 0xFFFFu) | (p[1] << 16);
                ch.u.y = (p[2] & 0xFFFFu) | (p[3] << 16);
                ch.u.z = (p[4] & 0xFFFFu) | (p[5] << 16);
                ch.u.w = (p[6] & 0xFFFFu) | (p[7] << 16);
                cl.u.x = (p[0] >> 16) | (p[1] & 0xFFFF0000u);
                cl.u.y = (p[2] >> 16) | (p[3] & 0xFFFF0000u);
                cl.u.z = (p[4] >> 16) | (p[5] & 0xFFFF0000u);
                cl.u.w = (p[6] >> 16) | (p[7] & 0xFFFF0000u);
                xh = ch.v; xl = cl.v;
            }
            #pragma unroll
            for (int nt = 0; nt < 2; ++nt) {
                acc[mt][nt] = MFMA16(xh, bh[nt], acc[mt][nt]);
                acc[mt][nt] = MFMA16(xh, bl[nt], acc[mt][nt]);
                acc[mt][nt] = MFMA16(xl, bh[nt], acc[mt][nt]);
            }
        }
    }

    // write Y (C-layout -> [combo][h] split-bf16 LDS)
    #pragma unroll
    for (int mt = 0; mt < 2; ++mt) {
        #pragma unroll
        for (int nt = 0; nt < 2; ++nt) {
            #pragma unroll
            for (int r = 0; r < 4; ++r) {
                const int h = wv * 32 + mt * 16 + q * 4 + r;
                const int combo = nt * 16 + mrow;
                const float val = acc[mt][nt][r];
                const u16 hi = f2bf(val);
                Yhi[combo * 260 + h] = hi;
                Ylo[combo * 260 + h] = f2bf(val - bf2f(hi));
            }
        }
    }
    __syncthreads();

    // ---- stage 2: P[32,32] = EB * Y (waves 0-3) ----
    if (wv < 4) {
        const int mt2 = wv >> 1, nt2 = wv & 1;
        f32x4 p = {};
        for (int ks = 0; ks < 8; ++ks) {
            const int aoff = (mt2 * 16 + mrow) * 256 + ks * 32 + q * 8;
            const bf16x8 ah = *(const bf16x8*)(ebhi + aoff);
            const bf16x8 al = *(const bf16x8*)(eblo + aoff);
            const int boff = (nt2 * 16 + mrow) * 260 + ks * 32 + q * 8;
            const bf16x8 yh = *(const bf16x8*)(Yhi + boff);
            const bf16x8 yl = *(const bf16x8*)(Ylo + boff);
            p = MFMA16(ah, yh, p);
            p = MFMA16(ah, yl, p);
            p = MFMA16(al, yh, p);
        }
        #pragma unroll
        for (int r = 0; r < 4; ++r)
            P[mt2 * 16 + q * 4 + r][nt2 * 16 + mrow] = p[r];
    }
    __syncthreads();

    // ---- combine + store: Zr = Pcc - Pss, Zi = -(Pcs + Psc) ----
    if (tid < 256) {
        const int k = tid >> 4, l = tid & 15;
        const float zr = P[k][l] - P[16 + k][16 + l];
        const float zi = -(P[k][16 + l] + P[16 + k][l]);
        const int idx = (gb * NC + c) * 256 + tid;
        zred[idx * 2 + 0] = zr;
        zred[idx * 2 + 1] = zi;
    }
}

// ---------------------------------------------------------------------------
// Mode mix (round-4 form): grid (oc=32, mq=4, g=G); block 256 = 4 ich x 64 m.
// ---------------------------------------------------------------------------
__global__ __launch_bounds__(256) void mix_kernel(
    const float* __restrict__ zred,
    float* __restrict__ zmix,
    const float* __restrict__ wr,
    const float* __restrict__ wi,
    int o0, int n, int zgmul)
{
    __shared__ float ps[4][NB][64][2];
    const int tid = threadIdx.x;
    const int oc = blockIdx.x, mq = blockIdx.y, g = blockIdx.z;
    const int o = o0 + g, zg = zgmul * g;
    const int ichunk = tid >> 6, ml = tid & 63;
    const int mode = mq * 64 + ml;

    const float* wrb = wr + (size_t)(o * 4 + n) * NC * NC * 256;
    const float* wib = wi + (size_t)(o * 4 + n) * NC * NC * 256;

    float orr[NB] = {0.f, 0.f, 0.f, 0.f};
    float oii[NB] = {0.f, 0.f, 0.f, 0.f};

    #pragma unroll
    for (int ii = 0; ii < 8; ++ii) {
        const int i = ichunk * 8 + ii;
        const float wrv = wrb[(i * NC + oc) * 256 + mode];
        const float wiv = wib[(i * NC + oc) * 256 + mode];
        #pragma unroll
        for (int b = 0; b < NB; ++b) {
            const float2 z = *(const float2*)&zred[(((zg * NB + b) * NC + i) * 256 + mode) * 2];
            orr[b] += z.x * wrv - z.y * wiv;
            oii[b] += z.x * wiv + z.y * wrv;
        }
    }
    #pragma unroll
    for (int b = 0; b < NB; ++b) {
        ps[ichunk][b][ml][0] = orr[b];
        ps[ichunk][b][ml][1] = oii[b];
    }
    __syncthreads();

    const int b2 = tid >> 6, ml2 = tid & 63;
    float re = 0.f, im = 0.f;
    #pragma unroll
    for (int ic = 0; ic < 4; ++ic) {
        re += ps[ic][b2][ml2][0];
        im += ps[ic][b2][ml2][1];
    }
    const int oidx = ((g * NB + b2) * NC + oc) * 256 + mq * 64 + ml2;
    zmix[oidx * 2 + 0] = re;
    zmix[oidx * 2 + 1] = im;
}

// ---------------------------------------------------------------------------
// Inverse transform + bypass + GELU (+ fused projection), split-bf16 MFMA.
// Round-4 core; xb I/O is PACKED u32 (extract on load, packsplit on store).
// grid: (h=256, gb=G*4), block 256.
// ---------------------------------------------------------------------------
template<bool LIFT, bool FINAL>
__global__ __launch_bounds__(256) void inv_kernel(
    const float* __restrict__ zmix,
    const void* __restrict__ srcv,      // LIFT ? float x : u32 xb
    const float* __restrict__ byp_w,
    const float* __restrict__ byp_b,
    const float* __restrict__ lift_w,
    const float* __restrict__ lift_b,
    const float* __restrict__ proj_w,
    const float* __restrict__ proj_b,
    const u16* __restrict__ cwhi,
    const u16* __restrict__ cwlo,
    void* __restrict__ dstv,            // FINAL ? float out : u32 xb
    int o0, int n)
{
    __shared__ float2 tw[256];
    __shared__ u16 Thi[NC * 40], Tlo[NC * 40];
    __shared__ u16 Whi[NC * 40], Wlo[NC * 40];
    __shared__ float bbl[NC];
    __shared__ float bweffs[NC * 3];

    const int tid = threadIdx.x;
    const int h = blockIdx.x;
    const int gb = blockIdx.y;
    const int g = gb >> 2, b = gb & 3;
    const int o = o0 + g;

    {
        float s, cs;
        sincospif((float)tid * (2.0f / 256.0f), &s, &cs);
        tw[tid] = make_float2(cs, s);
    }

    const float* bwp = byp_w + (size_t)(o * 4 + n) * NC * NC;
    const float* bbp = byp_b + (o * 4 + n) * NC;

    if (LIFT) {
        if (tid < 96) {
            const int oc = tid / 3, j = tid % 3;
            float s = 0.f;
            for (int ic = 0; ic < NC; ++ic) s += bwp[oc * NC + ic] * lift_w[ic * 3 + j];
            bweffs[oc * 3 + j] = s;
        } else if (tid < 128) {
            const int oc = tid - 96;
            float s = bbp[oc];
            for (int ic = 0; ic < NC; ++ic) s += bwp[oc * NC + ic] * lift_b[ic];
            bbl[oc] = s;
        }
    } else {
        if (tid < NC) bbl[tid] = bbp[tid];
    }
    __syncthreads();

    for (int idx = tid; idx < NC * NC; idx += 256) {
        const int c = idx >> 5, ic = idx & 31;
        float v;
        if (LIFT) v = (ic < 3) ? bweffs[c * 3 + ic] : 0.f;
        else      v = bwp[idx];
        const u16 hi = f2bf(v);
        Whi[c * 40 + ic] = hi;
        Wlo[c * 40 + ic] = f2bf(v - bf2f(hi));
    }

    // phase A: T[c][l] from zmix; bias folded into T[c][0]
    #pragma unroll
    for (int rep = 0; rep < 2; ++rep) {
        const int it = rep * 256 + tid;
        const int c = it >> 4, l = it & 15;
        const float sl = (l == 0 ? 1.0f : 2.0f) / 256.0f;
        const float* zp = zmix + ((size_t)(gb * NC + c) * 256 + l) * 2;
        float tr = 0.f, ti = 0.f;
        int m = 0;
        #pragma unroll
        for (int k = 0; k < NM; ++k) {
            const float2 z = *(const float2*)(zp + k * 32);
            const float2 t = tw[m];
            tr += z.x * t.x - z.y * t.y;
            ti += z.x * t.y + z.y * t.x;
            m = (m + h) & 255;
        }
        tr *= sl; ti *= sl;
        if (l == 0) tr += bbl[c];
        const u16 rh = f2bf(tr);
        Thi[c * 40 + l] = rh;
        Tlo[c * 40 + l] = f2bf(tr - bf2f(rh));
        const float nti_ = -ti;
        const u16 ih = f2bf(nti_);
        Thi[c * 40 + 16 + l] = ih;
        Tlo[c * 40 + 16 + l] = f2bf(nti_ - bf2f(ih));
    }
    __syncthreads();

    const int lane = tid & 63, wv = tid >> 6;
    const int mrow = lane & 15, q = lane >> 4;

    bf16x8 aThi[2], aTlo[2], aWhi[2], aWlo[2];
    #pragma unroll
    for (int mt = 0; mt < 2; ++mt) {
        const int ro = (mt * 16 + mrow) * 40 + 8 * q;
        aThi[mt] = *(const bf16x8*)&Thi[ro];
        aTlo[mt] = *(const bf16x8*)&Tlo[ro];
        aWhi[mt] = *(const bf16x8*)&Whi[ro];
        aWlo[mt] = *(const bf16x8*)&Wlo[ro];
    }

    float pwv[8];
    float pb = 0.f;
    if (FINAL) {
        #pragma unroll
        for (int mt = 0; mt < 2; ++mt)
            #pragma unroll
            for (int i = 0; i < 4; ++i)
                pwv[mt * 4 + i] = proj_w[mt * 16 + q * 4 + i];
        pb = proj_b[0];
    }

    const float* xbf = LIFT ? (const float*)srcv + (size_t)b * 3 * NPIX + h * NW : nullptr;
    const u32*   xbp = LIFT ? nullptr : (const u32*)srcv + (size_t)gb * NC * NPIX + h * NW;
    u32*   dstp = (u32*)dstv;
    float* dstf = (float*)dstv;

    for (int nti = 0; nti < 4; ++nti) {
        const int nt = wv * 4 + nti;
        const int ncol = nt * 16 + mrow;

        const bf16x8 cwh = *(const bf16x8*)(cwhi + ncol * 32 + 8 * q);
        const bf16x8 cwl = *(const bf16x8*)(cwlo + ncol * 32 + 8 * q);

        bf16x8 xh, xl;
        #pragma unroll
        for (int j = 0; j < 8; ++j) {
            const int k = 8 * q + j;
            if (LIFT) {
                const float v = (k < 3) ? xbf[(size_t)k * NPIX + ncol] : 0.f;
                const u16 hi = f2bf(v);
                xh[j] = (short)hi;
                xl[j] = (short)f2bf(v - bf2f(hi));
            } else {
                const u32 p = xbp[(size_t)k * NPIX + ncol];
                xh[j] = (short)(p & 0xFFFFu);
                xl[j] = (short)(p >> 16);
            }
        }

        float fpart = 0.f;
        #pragma unroll
        for (int mt = 0; mt < 2; ++mt) {
            f32x4 acc = {0.f, 0.f, 0.f, 0.f};
            acc = MFMA16(aThi[mt], cwh, acc);
            acc = MFMA16(aThi[mt], cwl, acc);
            acc = MFMA16(aTlo[mt], cwh, acc);
            acc = MFMA16(aWhi[mt], xh, acc);
            acc = MFMA16(aWhi[mt], xl, acc);
            acc = MFMA16(aWlo[mt], xh, acc);
            if (FINAL) {
                #pragma unroll
                for (int i = 0; i < 4; ++i)
                    fpart += gelu_fast(acc[i]) * pwv[mt * 4 + i];
            } else {
                #pragma unroll
                for (int i = 0; i < 4; ++i) {
                    const int c = mt * 16 + q * 4 + i;
                    dstp[((size_t)gb * NC + c) * NPIX + h * NW + ncol] = packsplit(gelu_fast(acc[i]));
                }
            }
        }
        if (FINAL) {
            fpart += __shfl_xor(fpart, 16);
            fpart += __shfl_xor(fpart, 32);
            if (q == 0) {
                dstf[(((size_t)b * 4 + o) * NH + h) * NW + nt * 16 + mrow] = fpart + pb;
            }
        }
    }
}

// ---------------------------------------------------------------------------
extern "C" void kernel_launch(void* const* d_in, const int* in_sizes, int n_in,
                              void* d_out, int out_size, void* d_ws, size_t ws_size,
                              hipStream_t stream)
{
    const float* x      = (const float*)d_in[0];
    const float* lift_w = (const float*)d_in[1];
    const float* lift_b = (const float*)d_in[2];
    const float* wr     = (const float*)d_in[3];
    const float* wi     = (const float*)d_in[4];
    const float* byp_w  = (const float*)d_in[5];
    const float* byp_b  = (const float*)d_in[6];
    const float* proj_w = (const float*)d_in[7];
    const float* proj_b = (const float*)d_in[8];
    float* ws  = (float*)d_ws;

    // ws: [cw/eb tables 16384 fl][zlift 65536][zred G*ZG][zmix G*ZG][bufA][bufB]
    u16* cwhi = (u16*)ws;
    u16* cwlo = cwhi + 8192;
    u16* ebhi = cwlo + 8192;
    u16* eblo = ebhi + 8192;
    float* base = ws + 16384;

    int G = 2;
    while (G > 1) {
        const size_t need = (16384 + 65536 + (size_t)2 * G * ZG + (size_t)2 * G * NP) * sizeof(float);
        if (need <= ws_size) break;
        G >>= 1;
    }

    float* zlift = base;
    float* zred  = zlift + 65536;
    float* zmix  = zred + (size_t)G * ZG;
    u32* bufA = (u32*)(zmix + (size_t)G * ZG);
    u32* bufB = bufA + (size_t)G * NP;

    tab_prep<<<64, 256, 0, stream>>>(cwhi, cwlo, ebhi, eblo);

    // lift spectrum is o-independent: compute once
    fwd_kernel<true><<<dim3(NC, NB), 512, 0, stream>>>(x, lift_w, lift_b, ebhi, eblo, zlift);

    for (int o0 = 0; o0 < 4; o0 += G) {
        const u32* rd = nullptr;
        u32* wrbuf = bufA;
        for (int n = 0; n < 4; ++n) {
            const bool lift = (n == 0);
            const bool fin  = (n == 3);

            if (!lift)
                fwd_kernel<false><<<dim3(NC, G * NB), 512, 0, stream>>>(rd, lift_w, lift_b, ebhi, eblo, zred);

            mix_kernel<<<dim3(NC, 4, G), 256, 0, stream>>>(
                lift ? zlift : zred, zmix, wr, wi, o0, n, lift ? 0 : 1);

            dim3 igrid(NH, G * NB);
            if (fin) {
                inv_kernel<false, true><<<igrid, 256, 0, stream>>>(
                    zmix, rd, byp_w, byp_b, lift_w, lift_b, proj_w, proj_b, cwhi, cwlo, d_out, o0, n);
            } else if (lift) {
                inv_kernel<true, false><<<igrid, 256, 0, stream>>>(
                    zmix, x, byp_w, byp_b, lift_w, lift_b, proj_w, proj_b, cwhi, cwlo, wrbuf, o0, n);
            } else {
                inv_kernel<false, false><<<igrid, 256, 0, stream>>>(
                    zmix, rd, byp_w, byp_b, lift_w, lift_b, proj_w, proj_b, cwhi, cwlo, wrbuf, o0, n);
            }
            rd = wrbuf;
            wrbuf = (wrbuf == bufA) ? bufB : bufA;
        }
    }
}

// Round 10
// 510.991 us; speedup vs baseline: 1.2536x; 1.0392x over previous
//
#include <hip/hip_runtime.h>

#define NB 4      // batch
#define NC 32     // width (channels)
#define NH 256
#define NW 256
#define NM 16     // modes per dim
constexpr int NPIX = NH * NW;                 // 65536
constexpr int NP = NB * NC * NPIX;            // elements per per-o tensor (u32-packed)
constexpr int ZG = NB * NC * NM * NM * 2;     // floats per g for zred/zmix

typedef short bf16x8 __attribute__((ext_vector_type(8)));
typedef float f32x4  __attribute__((ext_vector_type(4)));
typedef unsigned short u16;
typedef unsigned int u32;

#define MFMA16(a, b, c) __builtin_amdgcn_mfma_f32_16x16x32_bf16(a, b, c, 0, 0, 0)

__device__ __forceinline__ u16 f2bf(float f) {
    unsigned u = __float_as_uint(f);
    u += 0x7FFFu + ((u >> 16) & 1u);
    return (u16)(u >> 16);
}
__device__ __forceinline__ float bf2f(u16 h) {
    return __uint_as_float(((unsigned)h) << 16);
}
// pack fp32 -> (hi bf16) | (lo bf16 << 16); consumers use exactly hi+lo
__device__ __forceinline__ u32 packsplit(float f) {
    const u16 hi = f2bf(f);
    const u16 lo = f2bf(f - bf2f(hi));
    return (u32)hi | ((u32)lo << 16);
}

// fast erf (A&S 7.1.26, |err| <= 1.5e-7) based exact-GELU
__device__ __forceinline__ float gelu_fast(float v) {
    const float ax = fabsf(v) * 0.70710678118654752f;
    const float t = __builtin_amdgcn_rcpf(1.0f + 0.3275911f * ax);
    const float y = t * (0.254829592f + t * (-0.284496736f + t * (1.421413741f +
                    t * (-1.453152027f + t * 1.061405429f))));
    const float e = __expf(-ax * ax);
    float er = 1.0f - y * e;
    er = copysignf(er, v);
    return 0.5f * v * (1.0f + er);
}

// ---------------------------------------------------------------------------
// Table prep: cw (inv B-operand, [n=256][k=32]) and eb (fwd DFT matrix,
// [row=32][w=256], scaled 1/16; applied twice -> 1/256 ortho norm).
// ---------------------------------------------------------------------------
__global__ __launch_bounds__(256) void tab_prep(
    u16* __restrict__ cwhi, u16* __restrict__ cwlo,
    u16* __restrict__ ebhi, u16* __restrict__ eblo)
{
    const int id = blockIdx.x * 256 + threadIdx.x;   // 0..16383
    if (id < 8192) {
        const int nn = id >> 5, k = id & 31;
        const int m = ((k & 15) * nn) & 255;
        float s, c;
        sincospif((float)m * (2.0f / 256.0f), &s, &c);
        const float v = (k < 16) ? c : s;
        const u16 hi = f2bf(v);
        cwhi[id] = hi;
        cwlo[id] = f2bf(v - bf2f(hi));
    } else {
        const int id2 = id - 8192;
        const int row = id2 >> 8, w = id2 & 255;
        const int m = ((row & 15) * w) & 255;
        float s, c;
        sincospif((float)m * (2.0f / 256.0f), &s, &c);
        const float v = 0.0625f * ((row < 16) ? c : s);
        const u16 hi = f2bf(v);
        ebhi[id2] = hi;
        eblo[id2] = f2bf(v - bf2f(hi));
    }
}

// ---------------------------------------------------------------------------
// Lift stage 1 (once per call): Y_lift[b][h][c*32+combo] (packed u32) from x.
// grid (c=32, b=4, hq=4), block 256 (4 waves; wave wv owns rows q*4+r of its 16).
// Row-DFT math identical to verified round-6 s1; only the output layout is new.
// ---------------------------------------------------------------------------
__global__ __launch_bounds__(256) void s1_lift(
    const float* __restrict__ src,      // x[B,3,H,W]
    const float* __restrict__ lift_w,
    const float* __restrict__ lift_b,
    const u16* __restrict__ ebhi,
    const u16* __restrict__ eblo,
    u32* __restrict__ ypk)              // [b][h][1024]
{
    __shared__ u32 TrPk[64][33];        // [h-local][combo]

    const int tid = threadIdx.x;
    const int c  = blockIdx.x;
    const int b  = blockIdx.y;
    const int hq = blockIdx.z;
    const int wv = tid >> 6, lane = tid & 63;
    const int mrow = lane & 15, q = lane >> 4;
    const int hbase = hq * 64 + wv * 16;

    const float lw0 = lift_w[c * 3 + 0], lw1 = lift_w[c * 3 + 1], lw2 = lift_w[c * 3 + 2];
    const float lb = lift_b[c];
    const float* sb = src + (size_t)b * 3 * NPIX;

    f32x4 acc[2] = {};
    for (int ks = 0; ks < 8; ++ks) {
        bf16x8 bh[2], bl[2];
        #pragma unroll
        for (int nt = 0; nt < 2; ++nt) {
            const int off = (nt * 16 + mrow) * 256 + ks * 32 + q * 8;
            bh[nt] = *(const bf16x8*)(ebhi + off);
            bl[nt] = *(const bf16x8*)(eblo + off);
        }
        const float* xp = sb + (size_t)(hbase + mrow) * NW + ks * 32 + q * 8;
        const float4 p0a = *(const float4*)(xp);
        const float4 p0b = *(const float4*)(xp + 4);
        const float4 p1a = *(const float4*)(xp + NPIX);
        const float4 p1b = *(const float4*)(xp + NPIX + 4);
        const float4 p2a = *(const float4*)(xp + 2 * NPIX);
        const float4 p2b = *(const float4*)(xp + 2 * NPIX + 4);
        float v[8];
        v[0] = lw0 * p0a.x + lw1 * p1a.x + lw2 * p2a.x + lb;
        v[1] = lw0 * p0a.y + lw1 * p1a.y + lw2 * p2a.y + lb;
        v[2] = lw0 * p0a.z + lw1 * p1a.z + lw2 * p2a.z + lb;
        v[3] = lw0 * p0a.w + lw1 * p1a.w + lw2 * p2a.w + lb;
        v[4] = lw0 * p0b.x + lw1 * p1b.x + lw2 * p2b.x + lb;
        v[5] = lw0 * p0b.y + lw1 * p1b.y + lw2 * p2b.y + lb;
        v[6] = lw0 * p0b.z + lw1 * p1b.z + lw2 * p2b.z + lb;
        v[7] = lw0 * p0b.w + lw1 * p1b.w + lw2 * p2b.w + lb;
        bf16x8 xh, xl;
        #pragma unroll
        for (int j = 0; j < 8; ++j) {
            const u16 hi = f2bf(v[j]);
            xh[j] = (short)hi;
            xl[j] = (short)f2bf(v[j] - bf2f(hi));
        }
        #pragma unroll
        for (int nt = 0; nt < 2; ++nt) {
            acc[nt] = MFMA16(xh, bh[nt], acc[nt]);
            acc[nt] = MFMA16(xh, bl[nt], acc[nt]);
            acc[nt] = MFMA16(xl, bh[nt], acc[nt]);
        }
    }

    // C-layout: acc[nt][r] at (h-local = wv*16 + q*4 + r, combo = nt*16 + mrow)
    #pragma unroll
    for (int nt = 0; nt < 2; ++nt) {
        #pragma unroll
        for (int r = 0; r < 4; ++r)
            TrPk[wv * 16 + q * 4 + r][nt * 16 + mrow] = packsplit(acc[nt][r]);
    }
    __syncthreads();

    #pragma unroll
    for (int i = 0; i < 8; ++i) {
        const int idx = i * 256 + tid;
        const int hl = idx >> 5, combo = idx & 31;
        ypk[((size_t)b * 256 + hq * 64 + hl) * 1024 + c * 32 + combo] = TrPk[hl][combo];
    }
}

// ---------------------------------------------------------------------------
// s2: column-DFT P[kc][wc] = sum_h EB[kc][h] * Y[wc][h] + quadrant combine.
// Y comes in [gb][h][c*32+combo] packed; block (c,gb) loads its 32-wide slice
// of every h into LDS (transpose), then 4 waves = 2x2 tiles of P.
// grid (c=32, gb=ngb), block 256.
// ---------------------------------------------------------------------------
__global__ __launch_bounds__(256) void s2_kernel(
    const u32* __restrict__ ypk,
    const u16* __restrict__ ebhi,
    const u16* __restrict__ eblo,
    float* __restrict__ zred)
{
    __shared__ u32 Yl[256][33];         // [h][combo], pad 33
    __shared__ float P[32][33];

    const int tid = threadIdx.x;
    const int c  = blockIdx.x;
    const int gb = blockIdx.y;
    const int wv = tid >> 6, lane = tid & 63;
    const int mrow = lane & 15, q = lane >> 4;

    #pragma unroll
    for (int i = 0; i < 32; ++i) {
        const int idx = i * 256 + tid;
        const int h = idx >> 5, combo = idx & 31;
        Yl[h][combo] = ypk[((size_t)gb * 256 + h) * 1024 + c * 32 + combo];
    }
    __syncthreads();

    const int mt2 = wv >> 1, nt2 = wv & 1;
    const int wc = nt2 * 16 + mrow;
    f32x4 p = {};
    for (int ks = 0; ks < 8; ++ks) {
        const int aoff = (mt2 * 16 + mrow) * 256 + ks * 32 + q * 8;
        const bf16x8 ah = *(const bf16x8*)(ebhi + aoff);
        const bf16x8 al = *(const bf16x8*)(eblo + aoff);
        bf16x8 yh, yl;
        #pragma unroll
        for (int j = 0; j < 8; ++j) {
            const u32 v = Yl[ks * 32 + q * 8 + j][wc];
            yh[j] = (short)(v & 0xFFFFu);
            yl[j] = (short)(v >> 16);
        }
        p = MFMA16(ah, yh, p);
        p = MFMA16(ah, yl, p);
        p = MFMA16(al, yh, p);
    }
    #pragma unroll
    for (int r = 0; r < 4; ++r)
        P[mt2 * 16 + q * 4 + r][wc] = p[r];
    __syncthreads();

    // combine: Zr = Pcc - Pss, Zi = -(Pcs + Psc)
    const int k = tid >> 4, l = tid & 15;
    const float zr = P[k][l] - P[16 + k][16 + l];
    const float zi = -(P[k][16 + l] + P[16 + k][l]);
    const int idx = (gb * NC + c) * 256 + tid;
    zred[idx * 2 + 0] = zr;
    zred[idx * 2 + 1] = zi;
}

// ---------------------------------------------------------------------------
// Mode mix (round-9 form): grid (oc=32, mq=4, g=G); block 256.
// ---------------------------------------------------------------------------
__global__ __launch_bounds__(256) void mix_kernel(
    const float* __restrict__ zred,
    float* __restrict__ zmix,
    const float* __restrict__ wr,
    const float* __restrict__ wi,
    int o0, int n, int zgmul)
{
    __shared__ float ps[4][NB][64][2];
    const int tid = threadIdx.x;
    const int oc = blockIdx.x, mq = blockIdx.y, g = blockIdx.z;
    const int o = o0 + g, zg = zgmul * g;
    const int ichunk = tid >> 6, ml = tid & 63;
    const int mode = mq * 64 + ml;

    const float* wrb = wr + (size_t)(o * 4 + n) * NC * NC * 256;
    const float* wib = wi + (size_t)(o * 4 + n) * NC * NC * 256;

    float orr[NB] = {0.f, 0.f, 0.f, 0.f};
    float oii[NB] = {0.f, 0.f, 0.f, 0.f};

    #pragma unroll
    for (int ii = 0; ii < 8; ++ii) {
        const int i = ichunk * 8 + ii;
        const float wrv = wrb[(i * NC + oc) * 256 + mode];
        const float wiv = wib[(i * NC + oc) * 256 + mode];
        #pragma unroll
        for (int b = 0; b < NB; ++b) {
            const float2 z = *(const float2*)&zred[(((zg * NB + b) * NC + i) * 256 + mode) * 2];
            orr[b] += z.x * wrv - z.y * wiv;
            oii[b] += z.x * wiv + z.y * wrv;
        }
    }
    #pragma unroll
    for (int b = 0; b < NB; ++b) {
        ps[ichunk][b][ml][0] = orr[b];
        ps[ichunk][b][ml][1] = oii[b];
    }
    __syncthreads();

    const int b2 = tid >> 6, ml2 = tid & 63;
    float re = 0.f, im = 0.f;
    #pragma unroll
    for (int ic = 0; ic < 4; ++ic) {
        re += ps[ic][b2][ml2][0];
        im += ps[ic][b2][ml2][1];
    }
    const int oidx = ((g * NB + b2) * NC + oc) * 256 + mq * 64 + ml2;
    zmix[oidx * 2 + 0] = re;
    zmix[oidx * 2 + 1] = im;
}

// ---------------------------------------------------------------------------
// Inverse transform + bypass + GELU (+ projection if FINAL) + next layer's
// row-DFT Y if PRODY. Core = round-9 verified form; PRODY = round-7 verified
// math with the store path fixed: LDS-staged, one contiguous 4KB packed write.
// grid: (h=256, gb=G*4), block 256.
// ---------------------------------------------------------------------------
template<bool LIFT, bool FINAL, bool PRODY>
__global__ __launch_bounds__(256) void inv_kernel(
    const float* __restrict__ zmix,
    const void* __restrict__ srcv,      // LIFT ? float x : u32 xb
    const float* __restrict__ byp_w,
    const float* __restrict__ byp_b,
    const float* __restrict__ lift_w,
    const float* __restrict__ lift_b,
    const float* __restrict__ proj_w,
    const float* __restrict__ proj_b,
    const u16* __restrict__ cwhi,
    const u16* __restrict__ cwlo,
    const u16* __restrict__ ebhi,
    const u16* __restrict__ eblo,
    u32* __restrict__ ypk,              // [gb][h][1024] (PRODY)
    void* __restrict__ dstv,            // FINAL ? float out : u32 xb
    int o0, int n)
{
    __shared__ float2 tw[256];
    __shared__ u16 Thi[NC * 40], Tlo[NC * 40];
    __shared__ u16 Whi[NC * 40], Wlo[NC * 40];
    __shared__ float bbl[NC];
    __shared__ float bweffs[NC * 3];
    __shared__ u16 Ghi[PRODY ? 32 * 264 : 1];
    __shared__ u16 Glo[PRODY ? 32 * 264 : 1];
    __shared__ u32 Ypks[PRODY ? 1024 : 1];

    const int tid = threadIdx.x;
    const int h = blockIdx.x;
    const int gb = blockIdx.y;
    const int g = gb >> 2, b = gb & 3;
    const int o = o0 + g;

    {
        float s, cs;
        sincospif((float)tid * (2.0f / 256.0f), &s, &cs);
        tw[tid] = make_float2(cs, s);
    }

    const float* bwp = byp_w + (size_t)(o * 4 + n) * NC * NC;
    const float* bbp = byp_b + (o * 4 + n) * NC;

    if (LIFT) {
        if (tid < 96) {
            const int oc = tid / 3, j = tid % 3;
            float s = 0.f;
            for (int ic = 0; ic < NC; ++ic) s += bwp[oc * NC + ic] * lift_w[ic * 3 + j];
            bweffs[oc * 3 + j] = s;
        } else if (tid < 128) {
            const int oc = tid - 96;
            float s = bbp[oc];
            for (int ic = 0; ic < NC; ++ic) s += bwp[oc * NC + ic] * lift_b[ic];
            bbl[oc] = s;
        }
    } else {
        if (tid < NC) bbl[tid] = bbp[tid];
    }
    __syncthreads();

    for (int idx = tid; idx < NC * NC; idx += 256) {
        const int c = idx >> 5, ic = idx & 31;
        float v;
        if (LIFT) v = (ic < 3) ? bweffs[c * 3 + ic] : 0.f;
        else      v = bwp[idx];
        const u16 hi = f2bf(v);
        Whi[c * 40 + ic] = hi;
        Wlo[c * 40 + ic] = f2bf(v - bf2f(hi));
    }

    // phase A: T[c][l] from zmix; bias folded into T[c][0]
    #pragma unroll
    for (int rep = 0; rep < 2; ++rep) {
        const int it = rep * 256 + tid;
        const int c = it >> 4, l = it & 15;
        const float sl = (l == 0 ? 1.0f : 2.0f) / 256.0f;
        const float* zp = zmix + ((size_t)(gb * NC + c) * 256 + l) * 2;
        float tr = 0.f, ti = 0.f;
        int m = 0;
        #pragma unroll
        for (int k = 0; k < NM; ++k) {
            const float2 z = *(const float2*)(zp + k * 32);
            const float2 t = tw[m];
            tr += z.x * t.x - z.y * t.y;
            ti += z.x * t.y + z.y * t.x;
            m = (m + h) & 255;
        }
        tr *= sl; ti *= sl;
        if (l == 0) tr += bbl[c];
        const u16 rh = f2bf(tr);
        Thi[c * 40 + l] = rh;
        Tlo[c * 40 + l] = f2bf(tr - bf2f(rh));
        const float nti_ = -ti;
        const u16 ih = f2bf(nti_);
        Thi[c * 40 + 16 + l] = ih;
        Tlo[c * 40 + 16 + l] = f2bf(nti_ - bf2f(ih));
    }
    __syncthreads();

    const int lane = tid & 63, wv = tid >> 6;
    const int mrow = lane & 15, q = lane >> 4;

    bf16x8 aThi[2], aTlo[2], aWhi[2], aWlo[2];
    #pragma unroll
    for (int mt = 0; mt < 2; ++mt) {
        const int ro = (mt * 16 + mrow) * 40 + 8 * q;
        aThi[mt] = *(const bf16x8*)&Thi[ro];
        aTlo[mt] = *(const bf16x8*)&Tlo[ro];
        aWhi[mt] = *(const bf16x8*)&Whi[ro];
        aWlo[mt] = *(const bf16x8*)&Wlo[ro];
    }

    float pwv[8];
    float pb = 0.f;
    if (FINAL) {
        #pragma unroll
        for (int mt = 0; mt < 2; ++mt)
            #pragma unroll
            for (int i = 0; i < 4; ++i)
                pwv[mt * 4 + i] = proj_w[mt * 16 + q * 4 + i];
        pb = proj_b[0];
    }

    const float* xbf = LIFT ? (const float*)srcv + (size_t)b * 3 * NPIX + h * NW : nullptr;
    const u32*   xbp = LIFT ? nullptr : (const u32*)srcv + (size_t)gb * NC * NPIX + h * NW;
    u32*   dstp = (u32*)dstv;
    float* dstf = (float*)dstv;

    for (int nti = 0; nti < 4; ++nti) {
        const int nt = wv * 4 + nti;
        const int ncol = nt * 16 + mrow;

        const bf16x8 cwh = *(const bf16x8*)(cwhi + ncol * 32 + 8 * q);
        const bf16x8 cwl = *(const bf16x8*)(cwlo + ncol * 32 + 8 * q);

        bf16x8 xh, xl;
        #pragma unroll
        for (int j = 0; j < 8; ++j) {
            const int k = 8 * q + j;
            if (LIFT) {
                const float v = (k < 3) ? xbf[(size_t)k * NPIX + ncol] : 0.f;
                const u16 hi = f2bf(v);
                xh[j] = (short)hi;
                xl[j] = (short)f2bf(v - bf2f(hi));
            } else {
                const u32 p = xbp[(size_t)k * NPIX + ncol];
                xh[j] = (short)(p & 0xFFFFu);
                xl[j] = (short)(p >> 16);
            }
        }

        float fpart = 0.f;
        #pragma unroll
        for (int mt = 0; mt < 2; ++mt) {
            f32x4 acc = {0.f, 0.f, 0.f, 0.f};
            acc = MFMA16(aThi[mt], cwh, acc);
            acc = MFMA16(aThi[mt], cwl, acc);
            acc = MFMA16(aTlo[mt], cwh, acc);
            acc = MFMA16(aWhi[mt], xh, acc);
            acc = MFMA16(aWhi[mt], xl, acc);
            acc = MFMA16(aWlo[mt], xh, acc);
            if (FINAL) {
                #pragma unroll
                for (int i = 0; i < 4; ++i)
                    fpart += gelu_fast(acc[i]) * pwv[mt * 4 + i];
            } else {
                #pragma unroll
                for (int i = 0; i < 4; ++i) {
                    const int c = mt * 16 + q * 4 + i;
                    const float gl = gelu_fast(acc[i]);
                    dstp[((size_t)gb * NC + c) * NPIX + h * NW + ncol] = packsplit(gl);
                    if (PRODY) {
                        const u16 hi = f2bf(gl);
                        Ghi[c * 264 + ncol] = hi;
                        Glo[c * 264 + ncol] = f2bf(gl - bf2f(hi));
                    }
                }
            }
        }
        if (FINAL) {
            fpart += __shfl_xor(fpart, 16);
            fpart += __shfl_xor(fpart, 32);
            if (q == 0) {
                dstf[(((size_t)b * 4 + o) * NH + h) * NW + nt * 16 + mrow] = fpart + pb;
            }
        }
    }

    // ---- appended (PRODY): next layer's row-DFT for this (h, gb) ----
    if (PRODY) {
        __syncthreads();
        const int mt1 = wv >> 1, nt1 = wv & 1;   // 4 waves = 2x2 tiles
        f32x4 yacc = {};
        for (int ks = 0; ks < 8; ++ks) {
            const int ao = (mt1 * 16 + mrow) * 264 + ks * 32 + q * 8;
            const bf16x8 gh = *(const bf16x8*)&Ghi[ao];
            const bf16x8 gl = *(const bf16x8*)&Glo[ao];
            const int bo = (nt1 * 16 + mrow) * 256 + ks * 32 + q * 8;
            const bf16x8 bh = *(const bf16x8*)(ebhi + bo);
            const bf16x8 bl = *(const bf16x8*)(eblo + bo);
            yacc = MFMA16(gh, bh, yacc);
            yacc = MFMA16(gh, bl, yacc);
            yacc = MFMA16(gl, bh, yacc);
        }
        #pragma unroll
        for (int r = 0; r < 4; ++r) {
            const int c = mt1 * 16 + q * 4 + r;
            const int combo = nt1 * 16 + mrow;
            Ypks[c * 32 + combo] = packsplit(yacc[r]);
        }
        __syncthreads();
        u32* yout = ypk + ((size_t)gb * 256 + h) * 1024;
        #pragma unroll
        for (int i = 0; i < 4; ++i)
            yout[i * 256 + tid] = Ypks[i * 256 + tid];
    }
}

// ---------------------------------------------------------------------------
extern "C" void kernel_launch(void* const* d_in, const int* in_sizes, int n_in,
                              void* d_out, int out_size, void* d_ws, size_t ws_size,
                              hipStream_t stream)
{
    const float* x      = (const float*)d_in[0];
    const float* lift_w = (const float*)d_in[1];
    const float* lift_b = (const float*)d_in[2];
    const float* wr     = (const float*)d_in[3];
    const float* wi     = (const float*)d_in[4];
    const float* byp_w  = (const float*)d_in[5];
    const float* byp_b  = (const float*)d_in[6];
    const float* proj_w = (const float*)d_in[7];
    const float* proj_b = (const float*)d_in[8];
    float* ws  = (float*)d_ws;

    const int G = 2;

    // ws: [cw/eb tables 16384 fl][zlift 65536][ylift 1M u32][y 2M u32]
    //     [zred G*ZG][zmix G*ZG][bufA][bufB]
    u16* cwhi = (u16*)ws;
    u16* cwlo = cwhi + 8192;
    u16* ebhi = cwlo + 8192;
    u16* eblo = ebhi + 8192;
    float* zlift = ws + 16384;
    u32* ylift = (u32*)(zlift + 65536);                      // 4*256*1024
    u32* y     = ylift + (size_t)4 * 256 * 1024;             // 8*256*1024
    float* zred = (float*)(y + (size_t)G * NB * 256 * 1024);
    float* zmix = zred + (size_t)G * ZG;
    u32* bufA = (u32*)(zmix + (size_t)G * ZG);
    u32* bufB = bufA + (size_t)G * NP;

    tab_prep<<<64, 256, 0, stream>>>(cwhi, cwlo, ebhi, eblo);

    // lift spectrum is o-independent: stage-1 + stage-2 once
    s1_lift<<<dim3(NC, NB, 4), 256, 0, stream>>>(x, lift_w, lift_b, ebhi, eblo, ylift);
    s2_kernel<<<dim3(NC, NB), 256, 0, stream>>>(ylift, ebhi, eblo, zlift);

    for (int o0 = 0; o0 < 4; o0 += G) {
        const u32* rd = nullptr;
        u32* wrbuf = bufA;
        for (int n = 0; n < 4; ++n) {
            const bool lift = (n == 0);
            const bool fin  = (n == 3);

            if (!lift)
                s2_kernel<<<dim3(NC, G * NB), 256, 0, stream>>>(y, ebhi, eblo, zred);

            mix_kernel<<<dim3(NC, 4, G), 256, 0, stream>>>(
                lift ? zlift : zred, zmix, wr, wi, o0, n, lift ? 0 : 1);

            dim3 igrid(NH, G * NB);
            if (fin) {
                inv_kernel<false, true, false><<<igrid, 256, 0, stream>>>(
                    zmix, rd, byp_w, byp_b, lift_w, lift_b, proj_w, proj_b,
                    cwhi, cwlo, ebhi, eblo, y, d_out, o0, n);
            } else if (lift) {
                inv_kernel<true, false, true><<<igrid, 256, 0, stream>>>(
                    zmix, x, byp_w, byp_b, lift_w, lift_b, proj_w, proj_b,
                    cwhi, cwlo, ebhi, eblo, y, wrbuf, o0, n);
            } else {
                inv_kernel<false, false, true><<<igrid, 256, 0, stream>>>(
                    zmix, rd, byp_w, byp_b, lift_w, lift_b, proj_w, proj_b,
                    cwhi, cwlo, ebhi, eblo, y, wrbuf, o0, n);
            }
            rd = wrbuf;
            wrbuf = (wrbuf == bufA) ? bufB : bufA;
        }
    }
}